// Round 3
// baseline (964.067 us; speedup 1.0000x reference)
//
#include <hip/hip_runtime.h>
#include <hip/hip_bf16.h>
#include <math.h>

#define N_NODES 50000
#define N_EDGES 500000
#define DIM     128
#define NLAYER  4
#define NEFEAT  7

static constexpr float LN_EPS    = 1e-5f;
static constexpr float ATT_SCALE = 0.17677669529663687f;  // 1/sqrt(32)

typedef short s16x8 __attribute__((ext_vector_type(8)));   // 8 bf16 (4 VGPR) MFMA A/B frag
typedef float f32x4 __attribute__((ext_vector_type(4)));   // MFMA C/D frag

static __device__ __forceinline__ float leaky(float x){ return x >= 0.f ? x : 0.01f*x; }

static __device__ __forceinline__ unsigned short f2bf(float f){
    __hip_bfloat16 b = __float2bfloat16(f);
    return *reinterpret_cast<unsigned short*>(&b);
}
static __device__ __forceinline__ float bflo(unsigned int u){ return __uint_as_float(u << 16); }
static __device__ __forceinline__ float bfhi(unsigned int u){ return __uint_as_float(u & 0xFFFF0000u); }

static __device__ __forceinline__ void unpack8(uint4 eu, float* ea){
    ea[0]=bflo(eu.x); ea[1]=bfhi(eu.x); ea[2]=bflo(eu.y); ea[3]=bfhi(eu.y);
    ea[4]=bflo(eu.z); ea[5]=bfhi(eu.z); ea[6]=bflo(eu.w); ea[7]=bfhi(eu.w);
}

// ---------------- init h = node_table[0] broadcast (fp32 + bf16 shadow) ----------------
__global__ void init_h_kernel(const float* __restrict__ node_table,
                              float* __restrict__ h, unsigned short* __restrict__ hb){
    int i = blockIdx.x*blockDim.x + threadIdx.x;
    if (i < N_NODES*DIM){
        float v = node_table[i & (DIM-1)];
        h[i]  = v;
        hb[i] = f2bf(v);
    }
}

// ---------------- CSR build ----------------
__global__ void zero2_kernel(int* __restrict__ a, int* __restrict__ b){
    int i = blockIdx.x*blockDim.x + threadIdx.x;
    if (i < N_NODES){ a[i] = 0; b[i] = 0; }
}

__global__ void count_kernel(const int* __restrict__ dst, int* __restrict__ cnt){
    int e = blockIdx.x*blockDim.x + threadIdx.x;
    if (e < N_EDGES) atomicAdd(&cnt[dst[e]], 1);
}

__global__ void scan_kernel(const int* __restrict__ cnt, int* __restrict__ rowptr){
    __shared__ int wsum[16];
    __shared__ int runsh;
    if (threadIdx.x == 0) runsh = 0;
    __syncthreads();
    int lane = threadIdx.x & 63, wid = threadIdx.x >> 6;
    for (int base = 0; base < N_NODES; base += 1024){
        int i = base + (int)threadIdx.x;
        int vv = (i < N_NODES) ? cnt[i] : 0;
        int s = vv;
        #pragma unroll
        for (int off = 1; off < 64; off <<= 1){
            int t = __shfl_up(s, off);
            if (lane >= off) s += t;
        }
        if (lane == 63) wsum[wid] = s;
        __syncthreads();
        if (wid == 0 && lane < 16){
            int x = wsum[lane];
            #pragma unroll
            for (int off = 1; off < 16; off <<= 1){
                int t = __shfl_up(x, off);
                if (lane >= off) x += t;
            }
            wsum[lane] = x;
        }
        __syncthreads();
        int wpre = (wid == 0) ? 0 : wsum[wid-1];
        int run  = runsh;
        if (i < N_NODES) rowptr[i] = run + wpre + s - vv;   // exclusive
        __syncthreads();
        if (threadIdx.x == 0) runsh = run + wsum[15];
        __syncthreads();
    }
    if (threadIdx.x == 0) rowptr[N_NODES] = runsh;
}

__global__ void scatter_kernel(const int* __restrict__ src, const int* __restrict__ dst,
                               const float* __restrict__ edge_attr,
                               const int* __restrict__ rowptr, int* __restrict__ fill,
                               int* __restrict__ srcs, unsigned int* __restrict__ eab){
    int e = blockIdx.x*blockDim.x + threadIdx.x;
    if (e >= N_EDGES) return;
    int d   = dst[e];
    int pos = rowptr[d] + atomicAdd(&fill[d], 1);
    srcs[pos] = src[e];
    const float* a = edge_attr + (size_t)e*NEFEAT;
    uint4 u;
    u.x = (unsigned int)f2bf(a[0]) | ((unsigned int)f2bf(a[1]) << 16);
    u.y = (unsigned int)f2bf(a[2]) | ((unsigned int)f2bf(a[3]) << 16);
    u.z = (unsigned int)f2bf(a[4]) | ((unsigned int)f2bf(a[5]) << 16);
    u.w = (unsigned int)f2bf(a[6]) | (0x3F80u << 16);   // bias slot = 1.0
    *(uint4*)(eab + (size_t)pos*4) = u;
}

// ---------------- Weff[l] = [Wee@We_l ; bee@We_l + be_l]  (8 x 128), all layers ----------
__global__ void weff_all_kernel(const float* __restrict__ Wee, const float* __restrict__ bee,
                                const float* __restrict__ We, const float* __restrict__ be,
                                float* __restrict__ weff){
    int l = blockIdx.x;
    int d = threadIdx.x;  // 128 threads
    const float* We_l = We + (size_t)l*DIM*DIM;
    float* out = weff + (size_t)l*8*DIM;
    for (int c = 0; c < NEFEAT; ++c){
        float s = 0.f;
        for (int t = 0; t < DIM; ++t) s += Wee[c*DIM + t] * We_l[t*DIM + d];
        out[c*DIM + d] = s;
    }
    float s = 0.f;
    for (int t = 0; t < DIM; ++t) s += bee[t] * We_l[t*DIM + d];
    out[7*DIM + d] = s + be[l*DIM + d];
}

// ---------------- weight prep: bf16 transposed copies ----------------
__global__ void prepw_kernel(const float* __restrict__ Wq, const float* __restrict__ Wk,
                             const float* __restrict__ Wv, const float* __restrict__ Ws,
                             const float* __restrict__ W1, const float* __restrict__ W2,
                             unsigned short* __restrict__ wqkvsT,
                             unsigned short* __restrict__ w1T,
                             unsigned short* __restrict__ w2T){
    int tid = blockIdx.x*blockDim.x + threadIdx.x;
    if (tid >= NLAYER*131072) return;
    int l = tid >> 17;
    int r = tid & 131071;
    if (r < 65536){
        int n = r >> 7, k = r & 127;
        int p = n >> 7, nn = n & 127;
        const float* W = (p==0)?Wq:(p==1)?Wk:(p==2)?Wv:Ws;
        float val = W[(size_t)l*DIM*DIM + (size_t)k*DIM + nn];
        wqkvsT[(size_t)l*65536 + (size_t)n*128 + k] = f2bf(val);
    } else if (r < 98304){
        int r2 = r - 65536;
        int n = r2 >> 7, k = r2 & 127;
        float val = W1[(size_t)l*32768 + (size_t)k*256 + n];
        w1T[(size_t)l*32768 + (size_t)n*128 + k] = f2bf(val);
    } else {
        int r2 = r - 98304;
        int n = r2 >> 8, k = r2 & 255;
        float val = W2[(size_t)l*32768 + (size_t)k*128 + n];
        w2T[(size_t)l*32768 + (size_t)n*256 + k] = f2bf(val);
    }
}

// ---------------- QKVS GEMM via MFMA: [N,128]bf16 @ [128,512]bf16 ----------------
// grid (tiles, 2); 4 waves. y=0: parts q,k ; y=1: parts v,s.
// k -> low bf16 of kv[], v -> high bf16 of kv[] (byte-disjoint short stores, no race).
__global__ __launch_bounds__(256) void qkvs_mfma_kernel(
    const unsigned short* __restrict__ hb, const unsigned short* __restrict__ wT,
    const float* __restrict__ bq, const float* __restrict__ bk,
    const float* __restrict__ bv, const float* __restrict__ bs,
    unsigned short* __restrict__ q, unsigned int* __restrict__ kv,
    unsigned short* __restrict__ satt)
{
    __shared__ char sA[64*256];   // [64][128] bf16, XOR-swizzled
    int row0 = blockIdx.x*64;
    for (int idx = threadIdx.x; idx < 1024; idx += 256){
        int row = idx >> 4, k16 = idx & 15;
        int byte = row*256 + k16*16;  byte ^= (row & 7) << 4;
        s16x8 val = {0,0,0,0,0,0,0,0};
        int grow = row0 + row;
        if (grow < N_NODES) val = *(const s16x8*)(hb + (size_t)grow*128 + k16*8);
        *(s16x8*)(sA + byte) = val;
    }
    __syncthreads();

    int w = threadIdx.x >> 6, l = threadIdx.x & 63;
    int n0 = blockIdx.y*256 + w*64;
    f32x4 acc[4][4];
    #pragma unroll
    for (int rf=0;rf<4;++rf)
        #pragma unroll
        for (int cf=0;cf<4;++cf) acc[rf][cf] = (f32x4){0.f,0.f,0.f,0.f};

    s16x8 af[2][4], bf[2][4];
    #pragma unroll
    for (int rf=0;rf<4;++rf){
        int row = rf*16 + (l & 15);
        int byte = row*256 + (l >> 4)*16;  byte ^= (row & 7) << 4;
        af[0][rf] = *(const s16x8*)(sA + byte);
    }
    #pragma unroll
    for (int cf=0;cf<4;++cf){
        int n = n0 + cf*16 + (l & 15);
        bf[0][cf] = *(const s16x8*)(wT + (size_t)n*128 + (l >> 4)*8);
    }
    #pragma unroll
    for (int kb = 0; kb < 4; ++kb){
        int cur = kb & 1, nxt = cur ^ 1;
        if (kb < 3){
            #pragma unroll
            for (int rf=0;rf<4;++rf){
                int row = rf*16 + (l & 15);
                int byte = row*256 + (kb+1)*64 + (l >> 4)*16;  byte ^= (row & 7) << 4;
                af[nxt][rf] = *(const s16x8*)(sA + byte);
            }
            #pragma unroll
            for (int cf=0;cf<4;++cf){
                int n = n0 + cf*16 + (l & 15);
                bf[nxt][cf] = *(const s16x8*)(wT + (size_t)n*128 + (kb+1)*32 + (l >> 4)*8);
            }
        }
        #pragma unroll
        for (int rf=0;rf<4;++rf)
            #pragma unroll
            for (int cf=0;cf<4;++cf)
                acc[rf][cf] = __builtin_amdgcn_mfma_f32_16x16x32_bf16(af[cur][rf], bf[cur][cf], acc[rf][cf], 0, 0, 0);
    }

    int part = n0 >> 7;                      // 0:q 1:k 2:v 3:s
    int cip0 = n0 & 127;
    const float* bias = (part==0)?bq:(part==1)?bk:(part==2)?bv:bs;
    unsigned short* kvh = (unsigned short*)kv;
    #pragma unroll
    for (int cf=0;cf<4;++cf){
        int col = cip0 + cf*16 + (l & 15);
        float bb = bias[col];
        #pragma unroll
        for (int rf=0;rf<4;++rf){
            #pragma unroll
            for (int r=0;r<4;++r){
                int row = row0 + rf*16 + ((l >> 4) << 2) + r;
                if (row < N_NODES){
                    float val = acc[rf][cf][r] + bb;
                    size_t idx = (size_t)row*128 + col;
                    if      (part == 0) q[idx] = f2bf(val);
                    else if (part == 1) kvh[idx*2]     = f2bf(val);
                    else if (part == 2) kvh[idx*2 + 1] = f2bf(val);
                    else                satt[idx] = f2bf(val);
                }
            }
        }
    }
}

// ---------------- attention + skip + LN1 fused: one wave per destination node -----------
// alpha = q.k[src] + qe.ea ;  agg = (sum p*v + (sum p*ea)@Weff)/den
__global__ __launch_bounds__(256) void attn_kernel(
    const unsigned short* __restrict__ qq, const unsigned int* __restrict__ kv,
    const float* __restrict__ weff_l, const int* __restrict__ rowptr,
    const int* __restrict__ srcs, const unsigned int* __restrict__ eab,
    const unsigned short* __restrict__ satt, const float* __restrict__ h,
    const float* __restrict__ n1g, const float* __restrict__ n1b,
    unsigned short* __restrict__ x1b)
{
    __shared__ float wf[8][DIM];
    for (int i = threadIdx.x; i < 8*DIM; i += 256) ((float*)wf)[i] = weff_l[i];
    __syncthreads();
    int wv = threadIdx.x >> 6, lane = threadIdx.x & 63;
    int n = blockIdx.x*4 + wv;
    if (n >= N_NODES) return;
    int d0 = lane*2;

    // hoisted per-node loads
    float2 hv = *(const float2*)(h + (size_t)n*DIM + d0);
    unsigned int sab = *(const unsigned int*)(satt + (size_t)n*DIM + d0);
    float g0 = n1g[d0], g1 = n1g[d0+1], nb0 = n1b[d0], nb1 = n1b[d0+1];
    unsigned int qb = *(const unsigned int*)(qq + (size_t)n*DIM + d0);
    float q0 = bflo(qb)*ATT_SCALE, q1 = bfhi(qb)*ATT_SCALE;   // fold scale into q

    // qe[c] = sum_{d in head} q_d * Weff[c][d]  (head = 16-lane group)
    float qe[8];
    #pragma unroll
    for (int c = 0; c < 8; ++c){
        float2 wc = *(const float2*)&wf[c][d0];
        float p = q0*wc.x + q1*wc.y;
        p += __shfl_xor(p, 1); p += __shfl_xor(p, 2);
        p += __shfl_xor(p, 4); p += __shfl_xor(p, 8);
        qe[c] = p;
    }

    int beg = rowptr[n], end = rowptr[n+1];
    float m = 0.f, den = 0.f, a0 = 0.f, a1 = 0.f;
    float pea[8];
    #pragma unroll
    for (int c = 0; c < 8; ++c) pea[c] = 0.f;

    int i = beg;
    if (i < end){   // first edge initializes m (no -inf handling)
        int sv = srcs[i];
        uint2 kva = *(const uint2*)(kv + (size_t)sv*DIM + d0);
        uint4 eu  = *(const uint4*)(eab + (size_t)i*4);
        float ea[8]; unpack8(eu, ea);
        float p = q0*bflo(kva.x) + q1*bflo(kva.y);
        p += __shfl_xor(p, 1); p += __shfl_xor(p, 2);
        p += __shfl_xor(p, 4); p += __shfl_xor(p, 8);
        float al = p;
        #pragma unroll
        for (int c = 0; c < 8; ++c) al += qe[c]*ea[c];
        m = al; den = 1.f;
        a0 = bfhi(kva.x); a1 = bfhi(kva.y);
        #pragma unroll
        for (int c = 0; c < 8; ++c) pea[c] = ea[c];
        ++i;
    }
    for (; i + 1 < end; i += 2){
        int sv0 = srcs[i], sv1 = srcs[i+1];
        uint2 kva = *(const uint2*)(kv + (size_t)sv0*DIM + d0);
        uint2 kvb = *(const uint2*)(kv + (size_t)sv1*DIM + d0);
        uint4 eua = *(const uint4*)(eab + (size_t)i*4);
        uint4 eub = *(const uint4*)(eab + (size_t)(i+1)*4);
        float eaA[8], eaB[8];
        unpack8(eua, eaA); unpack8(eub, eaB);
        float va0 = bfhi(kva.x), va1 = bfhi(kva.y);
        float vb0 = bfhi(kvb.x), vb1 = bfhi(kvb.y);
        float pa = q0*bflo(kva.x) + q1*bflo(kva.y);
        float pb = q0*bflo(kvb.x) + q1*bflo(kvb.y);
        pa += __shfl_xor(pa, 1); pb += __shfl_xor(pb, 1);
        pa += __shfl_xor(pa, 2); pb += __shfl_xor(pb, 2);
        pa += __shfl_xor(pa, 4); pb += __shfl_xor(pb, 4);
        pa += __shfl_xor(pa, 8); pb += __shfl_xor(pb, 8);
        float alA = pa, alB = pb;
        #pragma unroll
        for (int c = 0; c < 8; ++c){ alA += qe[c]*eaA[c]; alB += qe[c]*eaB[c]; }
        float pmax = fmaxf(alA, alB);
        if (__builtin_expect(__all(pmax <= m + 8.f), 1)){   // defer-max fast path
            float p0 = __expf(alA - m), p1 = __expf(alB - m);
            den += p0 + p1;
            a0 += p0*va0 + p1*vb0;
            a1 += p0*va1 + p1*vb1;
            #pragma unroll
            for (int c = 0; c < 8; ++c) pea[c] += p0*eaA[c] + p1*eaB[c];
        } else {
            float nm = fmaxf(m, pmax);
            float f  = __expf(m - nm);
            float p0 = __expf(alA - nm), p1 = __expf(alB - nm);
            den = den*f + p0 + p1;
            a0 = a0*f + p0*va0 + p1*vb0;
            a1 = a1*f + p0*va1 + p1*vb1;
            #pragma unroll
            for (int c = 0; c < 8; ++c) pea[c] = pea[c]*f + p0*eaA[c] + p1*eaB[c];
            m = nm;
        }
    }
    if (i < end){   // tail edge
        int sv = srcs[i];
        uint2 kva = *(const uint2*)(kv + (size_t)sv*DIM + d0);
        uint4 eu  = *(const uint4*)(eab + (size_t)i*4);
        float ea[8]; unpack8(eu, ea);
        float v0 = bfhi(kva.x), v1 = bfhi(kva.y);
        float p = q0*bflo(kva.x) + q1*bflo(kva.y);
        p += __shfl_xor(p, 1); p += __shfl_xor(p, 2);
        p += __shfl_xor(p, 4); p += __shfl_xor(p, 8);
        float al = p;
        #pragma unroll
        for (int c = 0; c < 8; ++c) al += qe[c]*ea[c];
        if (__all(al <= m + 8.f)){
            float pp = __expf(al - m);
            den += pp; a0 += pp*v0; a1 += pp*v1;
            #pragma unroll
            for (int c = 0; c < 8; ++c) pea[c] += pp*ea[c];
        } else {
            float nm = fmaxf(m, al);
            float f  = __expf(m - nm);
            float pp = __expf(al - nm);
            den = den*f + pp; a0 = a0*f + pp*v0; a1 = a1*f + pp*v1;
            #pragma unroll
            for (int c = 0; c < 8; ++c) pea[c] = pea[c]*f + pp*ea[c];
        }
    }

    float inv = (den > 0.f) ? 1.f/den : 0.f;   // empty segment -> zeros
    float ev0 = 0.f, ev1 = 0.f;
    #pragma unroll
    for (int c = 0; c < 8; ++c){
        float2 wc = *(const float2*)&wf[c][d0];
        ev0 += pea[c]*wc.x; ev1 += pea[c]*wc.y;
    }
    float t0 = hv.x + (a0 + ev0)*inv + bflo(sab);
    float t1 = hv.y + (a1 + ev1)*inv + bfhi(sab);
    // LN1
    float sum = t0 + t1, ss = t0*t0 + t1*t1;
    #pragma unroll
    for (int off = 1; off < 64; off <<= 1){
        sum += __shfl_xor(sum, off);
        ss  += __shfl_xor(ss,  off);
    }
    float mu = sum * (1.f/DIM);
    float rstd = rsqrtf(ss*(1.f/DIM) - mu*mu + LN_EPS);
    float o0 = (t0-mu)*rstd*g0 + nb0;
    float o1 = (t1-mu)*rstd*g1 + nb1;
    unsigned int pk = (unsigned int)f2bf(o0) | ((unsigned int)f2bf(o1) << 16);
    *(unsigned int*)(x1b + (size_t)n*DIM + d0) = pk;
}

// ---------------- FFN via MFMA + LN2 + LN3 + act + residual ----------------
__global__ __launch_bounds__(256) void ffn_mfma_kernel(
    const unsigned short* __restrict__ x1b,
    const float* __restrict__ hin,
    const unsigned short* __restrict__ w1T, const float* __restrict__ b1,
    const unsigned short* __restrict__ w2T, const float* __restrict__ b2,
    const float* __restrict__ n2g, const float* __restrict__ n2b,
    const float* __restrict__ lng, const float* __restrict__ lnb,
    int apply_act, float* __restrict__ h, unsigned short* __restrict__ hb)
{
    __shared__ char smem[49152];
    char* sA   = smem;            // [64][128] bf16 swz (x1 tile)          16 KB
    char* sMid = smem + 16384;    // [64][256] bf16 swz (mid) -> later ffout [64][128] f32 swz
    int row0 = blockIdx.x*64;
    for (int idx = threadIdx.x; idx < 1024; idx += 256){
        int row = idx >> 4, k16 = idx & 15;
        int byte = row*256 + k16*16;  byte ^= (row & 7) << 4;
        s16x8 val = {0,0,0,0,0,0,0,0};
        int grow = row0 + row;
        if (grow < N_NODES) val = *(const s16x8*)(x1b + (size_t)grow*128 + k16*8);
        *(s16x8*)(sA + byte) = val;
    }
    __syncthreads();

    int w = threadIdx.x >> 6, l = threadIdx.x & 63;

    // ---- GEMM1: mid = leaky(x1 @ W1 + b1); wave w -> cols w*64..+63
    {
        int n0 = w*64;
        f32x4 acc[4][4];
        #pragma unroll
        for (int rf=0;rf<4;++rf)
            #pragma unroll
            for (int cf=0;cf<4;++cf) acc[rf][cf] = (f32x4){0.f,0.f,0.f,0.f};
        s16x8 af[2][4], bfr[2][4];
        #pragma unroll
        for (int rf=0;rf<4;++rf){
            int row = rf*16 + (l & 15);
            int byte = row*256 + (l >> 4)*16;  byte ^= (row & 7) << 4;
            af[0][rf] = *(const s16x8*)(sA + byte);
        }
        #pragma unroll
        for (int cf=0;cf<4;++cf){
            int n = n0 + cf*16 + (l & 15);
            bfr[0][cf] = *(const s16x8*)(w1T + (size_t)n*128 + (l >> 4)*8);
        }
        #pragma unroll
        for (int kb = 0; kb < 4; ++kb){
            int cur = kb & 1, nxt = cur ^ 1;
            if (kb < 3){
                #pragma unroll
                for (int rf=0;rf<4;++rf){
                    int row = rf*16 + (l & 15);
                    int byte = row*256 + (kb+1)*64 + (l >> 4)*16;  byte ^= (row & 7) << 4;
                    af[nxt][rf] = *(const s16x8*)(sA + byte);
                }
                #pragma unroll
                for (int cf=0;cf<4;++cf){
                    int n = n0 + cf*16 + (l & 15);
                    bfr[nxt][cf] = *(const s16x8*)(w1T + (size_t)n*128 + (kb+1)*32 + (l >> 4)*8);
                }
            }
            #pragma unroll
            for (int rf=0;rf<4;++rf)
                #pragma unroll
                for (int cf=0;cf<4;++cf)
                    acc[rf][cf] = __builtin_amdgcn_mfma_f32_16x16x32_bf16(af[cur][rf], bfr[cur][cf], acc[rf][cf], 0, 0, 0);
        }
        #pragma unroll
        for (int cf=0;cf<4;++cf){
            int col = n0 + cf*16 + (l & 15);
            float bb = b1[col];
            #pragma unroll
            for (int rf=0;rf<4;++rf){
                #pragma unroll
                for (int r=0;r<4;++r){
                    int row = rf*16 + ((l >> 4) << 2) + r;
                    float val = leaky(acc[rf][cf][r] + bb);
                    int byte = row*512 + col*2;  byte ^= (row & 7) << 4;
                    *(unsigned short*)(sMid + byte) = f2bf(val);
                }
            }
        }
    }
    __syncthreads();

    // ---- GEMM2: ff = mid @ W2; wave w -> cols w*32..+31; K=256
    f32x4 acc2[2][4];
    {
        int n0 = w*32;
        #pragma unroll
        for (int cf=0;cf<2;++cf)
            #pragma unroll
            for (int rf=0;rf<4;++rf) acc2[cf][rf] = (f32x4){0.f,0.f,0.f,0.f};
        s16x8 af[2][4], bfr[2][2];
        #pragma unroll
        for (int rf=0;rf<4;++rf){
            int row = rf*16 + (l & 15);
            int byte = row*512 + (l >> 4)*16;  byte ^= (row & 7) << 4;
            af[0][rf] = *(const s16x8*)(sMid + byte);
        }
        #pragma unroll
        for (int cf=0;cf<2;++cf){
            int n = n0 + cf*16 + (l & 15);
            bfr[0][cf] = *(const s16x8*)(w2T + (size_t)n*256 + (l >> 4)*8);
        }
        #pragma unroll
        for (int kb = 0; kb < 8; ++kb){
            int cur = kb & 1, nxt = cur ^ 1;
            if (kb < 7){
                #pragma unroll
                for (int rf=0;rf<4;++rf){
                    int row = rf*16 + (l & 15);
                    int byte = row*512 + (kb+1)*64 + (l >> 4)*16;  byte ^= (row & 7) << 4;
                    af[nxt][rf] = *(const s16x8*)(sMid + byte);
                }
                #pragma unroll
                for (int cf=0;cf<2;++cf){
                    int n = n0 + cf*16 + (l & 15);
                    bfr[nxt][cf] = *(const s16x8*)(w2T + (size_t)n*256 + (kb+1)*32 + (l >> 4)*8);
                }
            }
            #pragma unroll
            for (int cf=0;cf<2;++cf)
                #pragma unroll
                for (int rf=0;rf<4;++rf)
                    acc2[cf][rf] = __builtin_amdgcn_mfma_f32_16x16x32_bf16(af[cur][rf], bfr[cur][cf], acc2[cf][rf], 0, 0, 0);
        }
    }
    __syncthreads();   // all GEMM2 reads of sMid done; reuse as ffout f32

    float* sFF = (float*)sMid;
    {
        int n0 = w*32;
        #pragma unroll
        for (int cf=0;cf<2;++cf){
            int col = n0 + cf*16 + (l & 15);
            float bb = b2[col];
            #pragma unroll
            for (int rf=0;rf<4;++rf){
                #pragma unroll
                for (int r=0;r<4;++r){
                    int row = rf*16 + ((l >> 4) << 2) + r;
                    int byte = row*512 + col*4;  byte ^= (row & 7) << 4;
                    *(float*)((char*)sFF + byte) = acc2[cf][rf][r] + bb;
                }
            }
        }
    }
    __syncthreads();

    // ---- LN chain: c = LN2(x1+ff), hn = LN3(c), act, h = hn + h_in
    int d0 = l*2;
    float g2a = n2g[d0], g2b = n2g[d0+1], be2a = n2b[d0], be2b = n2b[d0+1];
    float gla = lng[d0], glb = lng[d0+1], bla = lnb[d0], blb = lnb[d0+1];
    for (int i = 0; i < 16; ++i){
        int rr = w*16 + i;
        int grow = row0 + rr;
        if (grow >= N_NODES) break;
        int byte = rr*512 + d0*4;  byte ^= (rr & 7) << 4;
        float2 ff = *(float2*)((char*)sFF + byte);
        int byteA = rr*256 + d0*2;  byteA ^= (rr & 7) << 4;
        unsigned int xu = *(unsigned int*)(sA + byteA);   // x1 residual from LDS bf16
        float2 hr = *(const float2*)(hin + (size_t)grow*DIM + d0);
        float t0 = bflo(xu) + ff.x, t1 = bfhi(xu) + ff.y;
        float sum = t0 + t1, ss = t0*t0 + t1*t1;
        #pragma unroll
        for (int off = 1; off < 64; off <<= 1){
            sum += __shfl_xor(sum, off);
            ss  += __shfl_xor(ss,  off);
        }
        float mu = sum*(1.f/DIM);
        float rstd = rsqrtf(ss*(1.f/DIM) - mu*mu + LN_EPS);
        float c0 = (t0-mu)*rstd*g2a + be2a;
        float c1 = (t1-mu)*rstd*g2b + be2b;
        float sum2 = c0 + c1, ss2 = c0*c0 + c1*c1;
        #pragma unroll
        for (int off = 1; off < 64; off <<= 1){
            sum2 += __shfl_xor(sum2, off);
            ss2  += __shfl_xor(ss2,  off);
        }
        float mu2 = sum2*(1.f/DIM);
        float rstd2 = rsqrtf(ss2*(1.f/DIM) - mu2*mu2 + LN_EPS);
        float z0 = (c0-mu2)*rstd2*gla + bla;
        float z1 = (c1-mu2)*rstd2*glb + blb;
        if (apply_act){ z0 = leaky(z0); z1 = leaky(z1); }
        float o0 = z0 + hr.x, o1 = z1 + hr.y;
        *(float2*)(h + (size_t)grow*DIM + d0) = make_float2(o0, o1);
        unsigned int pk = (unsigned int)f2bf(o0) | ((unsigned int)f2bf(o1) << 16);
        *(unsigned int*)(hb + (size_t)grow*DIM + d0) = pk;
    }
}

extern "C" void kernel_launch(void* const* d_in, const int* in_sizes, int n_in,
                              void* d_out, int out_size, void* d_ws, size_t ws_size,
                              hipStream_t stream)
{
    const int*   edge_index = (const int*)  d_in[1];
    const float* edge_attr  = (const float*)d_in[2];
    const float* node_table = (const float*)d_in[3];
    const float* Wee = (const float*)d_in[4];
    const float* bee = (const float*)d_in[5];
    const float* Wq  = (const float*)d_in[6];  const float* bq = (const float*)d_in[7];
    const float* Wk  = (const float*)d_in[8];  const float* bk = (const float*)d_in[9];
    const float* Wv  = (const float*)d_in[10]; const float* bv = (const float*)d_in[11];
    const float* We  = (const float*)d_in[12]; const float* be = (const float*)d_in[13];
    const float* Ws  = (const float*)d_in[14]; const float* bs = (const float*)d_in[15];
    const float* W1  = (const float*)d_in[16]; const float* b1 = (const float*)d_in[17];
    const float* W2  = (const float*)d_in[18]; const float* b2 = (const float*)d_in[19];
    const float* n1g = (const float*)d_in[20]; const float* n1b = (const float*)d_in[21];
    const float* n2g = (const float*)d_in[22]; const float* n2b = (const float*)d_in[23];
    const float* lng = (const float*)d_in[24]; const float* lnb = (const float*)d_in[25];

    float* h = (float*)d_out;

    char* ws = (char*)d_ws;
    size_t off = 0;
    auto alloc = [&](size_t bytes)->void*{
        void* p = ws + off;
        off += (bytes + 255) & ~(size_t)255;
        return p;
    };
    unsigned short* q    = (unsigned short*)alloc(sizeof(short)*(size_t)N_NODES*DIM);
    unsigned int*   kv   = (unsigned int*)  alloc(sizeof(int)*(size_t)N_NODES*DIM);
    unsigned short* hb   = (unsigned short*)alloc(sizeof(short)*(size_t)N_NODES*DIM);
    unsigned short* x1b  = (unsigned short*)alloc(sizeof(short)*(size_t)N_NODES*DIM);
    unsigned short* satt = (unsigned short*)alloc(sizeof(short)*(size_t)N_NODES*DIM);
    unsigned int*   eab  = (unsigned int*)  alloc(sizeof(int)*(size_t)N_EDGES*4);
    unsigned short* wqkvsT = (unsigned short*)alloc(sizeof(short)*NLAYER*512*128);
    unsigned short* w1T    = (unsigned short*)alloc(sizeof(short)*NLAYER*256*128);
    unsigned short* w2T    = (unsigned short*)alloc(sizeof(short)*NLAYER*128*256);
    float* weff = (float*)alloc(sizeof(float)*NLAYER*8*DIM);
    int* rowptr = (int*)alloc(sizeof(int)*(N_NODES+1));
    int* cnt    = (int*)alloc(sizeof(int)*N_NODES);
    int* fill   = (int*)alloc(sizeof(int)*N_NODES);
    int* srcs   = (int*)alloc(sizeof(int)*N_EDGES);

    const int* srcIdx = edge_index;
    const int* dstIdx = edge_index + N_EDGES;

    init_h_kernel<<<(N_NODES*DIM+255)/256, 256, 0, stream>>>(node_table, h, hb);
    zero2_kernel<<<(N_NODES+255)/256, 256, 0, stream>>>(cnt, fill);
    count_kernel<<<(N_EDGES+255)/256, 256, 0, stream>>>(dstIdx, cnt);
    scan_kernel<<<1, 1024, 0, stream>>>(cnt, rowptr);
    scatter_kernel<<<(N_EDGES+255)/256, 256, 0, stream>>>(srcIdx, dstIdx, edge_attr,
                                                          rowptr, fill, srcs, eab);
    prepw_kernel<<<(NLAYER*131072+255)/256, 256, 0, stream>>>(Wq, Wk, Wv, Ws, W1, W2,
                                                              wqkvsT, w1T, w2T);
    weff_all_kernel<<<NLAYER, 128, 0, stream>>>(Wee, bee, We, be, weff);

    int tiles = (N_NODES + 63)/64;
    for (int l = 0; l < NLAYER; ++l){
        qkvs_mfma_kernel<<<dim3(tiles, 2), 256, 0, stream>>>(hb,
            wqkvsT + (size_t)l*65536,
            bq + (size_t)l*DIM, bk + (size_t)l*DIM, bv + (size_t)l*DIM, bs + (size_t)l*DIM,
            q, kv, satt);
        attn_kernel<<<(N_NODES+3)/4, 256, 0, stream>>>(q, kv,
            weff + (size_t)l*8*DIM, rowptr, srcs, eab, satt, h,
            n1g + (size_t)l*DIM, n1b + (size_t)l*DIM, x1b);
        ffn_mfma_kernel<<<tiles, 256, 0, stream>>>(x1b, h,
            w1T + (size_t)l*32768, b1 + (size_t)l*2*DIM,
            w2T + (size_t)l*32768, b2 + (size_t)l*DIM,
            n2g + (size_t)l*DIM, n2b + (size_t)l*DIM,
            lng + (size_t)l*DIM, lnb + (size_t)l*DIM,
            (l < NLAYER-1) ? 1 : 0, h, hb);
    }
}

// Round 5
// 898.681 us; speedup vs baseline: 1.0728x; 1.0728x over previous
//
#include <hip/hip_runtime.h>
#include <hip/hip_bf16.h>
#include <math.h>

#define N_NODES 50000
#define N_EDGES 500000
#define DIM     128
#define NLAYER  4
#define NEFEAT  7

static constexpr float LN_EPS    = 1e-5f;
static constexpr float ATT_SCALE = 0.17677669529663687f;  // 1/sqrt(32)

typedef short s16x8 __attribute__((ext_vector_type(8)));   // 8 bf16 (4 VGPR) MFMA A/B frag
typedef float f32x4 __attribute__((ext_vector_type(4)));   // MFMA C/D frag

static __device__ __forceinline__ float leaky(float x){ return x >= 0.f ? x : 0.01f*x; }

static __device__ __forceinline__ unsigned short f2bf(float f){
    __hip_bfloat16 b = __float2bfloat16(f);
    return *reinterpret_cast<unsigned short*>(&b);
}
static __device__ __forceinline__ float bflo(unsigned int u){ return __uint_as_float(u << 16); }
static __device__ __forceinline__ float bfhi(unsigned int u){ return __uint_as_float(u & 0xFFFF0000u); }

// ---------------- init h = node_table[0] broadcast (fp32 + bf16 shadow) ----------------
__global__ void init_h_kernel(const float* __restrict__ node_table,
                              float* __restrict__ h, unsigned short* __restrict__ hb){
    int i = blockIdx.x*blockDim.x + threadIdx.x;
    if (i < N_NODES*DIM){
        float v = node_table[i & (DIM-1)];
        h[i]  = v;
        hb[i] = f2bf(v);
    }
}

// ---------------- CSR build ----------------
__global__ void zero2_kernel(int* __restrict__ a, int* __restrict__ b){
    int i = blockIdx.x*blockDim.x + threadIdx.x;
    if (i < N_NODES){ a[i] = 0; b[i] = 0; }
}

__global__ void count_kernel(const int* __restrict__ dst, int* __restrict__ cnt){
    int e = blockIdx.x*blockDim.x + threadIdx.x;
    if (e < N_EDGES) atomicAdd(&cnt[dst[e]], 1);
}

__global__ void scan_kernel(const int* __restrict__ cnt, int* __restrict__ rowptr){
    __shared__ int wsum[16];
    __shared__ int runsh;
    if (threadIdx.x == 0) runsh = 0;
    __syncthreads();
    int lane = threadIdx.x & 63, wid = threadIdx.x >> 6;
    for (int base = 0; base < N_NODES; base += 1024){
        int i = base + (int)threadIdx.x;
        int vv = (i < N_NODES) ? cnt[i] : 0;
        int s = vv;
        #pragma unroll
        for (int off = 1; off < 64; off <<= 1){
            int t = __shfl_up(s, off);
            if (lane >= off) s += t;
        }
        if (lane == 63) wsum[wid] = s;
        __syncthreads();
        if (wid == 0 && lane < 16){
            int x = wsum[lane];
            #pragma unroll
            for (int off = 1; off < 16; off <<= 1){
                int t = __shfl_up(x, off);
                if (lane >= off) x += t;
            }
            wsum[lane] = x;
        }
        __syncthreads();
        int wpre = (wid == 0) ? 0 : wsum[wid-1];
        int run  = runsh;
        if (i < N_NODES) rowptr[i] = run + wpre + s - vv;   // exclusive
        __syncthreads();
        if (threadIdx.x == 0) runsh = run + wsum[15];
        __syncthreads();
    }
    if (threadIdx.x == 0) rowptr[N_NODES] = runsh;
}

__global__ void scatter_kernel(const int* __restrict__ src, const int* __restrict__ dst,
                               const float* __restrict__ edge_attr,
                               const int* __restrict__ rowptr, int* __restrict__ fill,
                               int* __restrict__ srcs, unsigned int* __restrict__ eab){
    int e = blockIdx.x*blockDim.x + threadIdx.x;
    if (e >= N_EDGES) return;
    int d   = dst[e];
    int pos = rowptr[d] + atomicAdd(&fill[d], 1);
    srcs[pos] = src[e];
    const float* a = edge_attr + (size_t)e*NEFEAT;
    uint4 u;
    u.x = (unsigned int)f2bf(a[0]) | ((unsigned int)f2bf(a[1]) << 16);
    u.y = (unsigned int)f2bf(a[2]) | ((unsigned int)f2bf(a[3]) << 16);
    u.z = (unsigned int)f2bf(a[4]) | ((unsigned int)f2bf(a[5]) << 16);
    u.w = (unsigned int)f2bf(a[6]) | (0x3F80u << 16);   // bias slot = 1.0
    *(uint4*)(eab + (size_t)pos*4) = u;
}

// ---------------- Weff[l] = [Wee@We_l ; bee@We_l + be_l]  (8 x 128), all layers ----------
__global__ void weff_all_kernel(const float* __restrict__ Wee, const float* __restrict__ bee,
                                const float* __restrict__ We, const float* __restrict__ be,
                                float* __restrict__ weff){
    int l = blockIdx.x;
    int d = threadIdx.x;  // 128 threads
    const float* We_l = We + (size_t)l*DIM*DIM;
    float* out = weff + (size_t)l*8*DIM;
    for (int c = 0; c < NEFEAT; ++c){
        float s = 0.f;
        for (int t = 0; t < DIM; ++t) s += Wee[c*DIM + t] * We_l[t*DIM + d];
        out[c*DIM + d] = s;
    }
    float s = 0.f;
    for (int t = 0; t < DIM; ++t) s += bee[t] * We_l[t*DIM + d];
    out[7*DIM + d] = s + be[l*DIM + d];
}

// ---------------- weight prep: bf16 transposed copies ----------------
__global__ void prepw_kernel(const float* __restrict__ Wq, const float* __restrict__ Wk,
                             const float* __restrict__ Wv, const float* __restrict__ Ws,
                             const float* __restrict__ W1, const float* __restrict__ W2,
                             unsigned short* __restrict__ wqkvsT,
                             unsigned short* __restrict__ w1T,
                             unsigned short* __restrict__ w2T){
    int tid = blockIdx.x*blockDim.x + threadIdx.x;
    if (tid >= NLAYER*131072) return;
    int l = tid >> 17;
    int r = tid & 131071;
    if (r < 65536){
        int n = r >> 7, k = r & 127;
        int p = n >> 7, nn = n & 127;
        const float* W = (p==0)?Wq:(p==1)?Wk:(p==2)?Wv:Ws;
        float val = W[(size_t)l*DIM*DIM + (size_t)k*DIM + nn];
        wqkvsT[(size_t)l*65536 + (size_t)n*128 + k] = f2bf(val);
    } else if (r < 98304){
        int r2 = r - 65536;
        int n = r2 >> 7, k = r2 & 127;
        float val = W1[(size_t)l*32768 + (size_t)k*256 + n];
        w1T[(size_t)l*32768 + (size_t)n*128 + k] = f2bf(val);
    } else {
        int r2 = r - 98304;
        int n = r2 >> 8, k = r2 & 255;
        float val = W2[(size_t)l*32768 + (size_t)k*128 + n];
        w2T[(size_t)l*32768 + (size_t)n*256 + k] = f2bf(val);
    }
}

// ---------------- QKVS GEMM via MFMA: [N,128]bf16 @ [128,512]bf16 ----------------
// grid (tiles, 2); 4 waves, 64 rows/tile.
// y=0: parts {q (w-rows 0-127), s (384-511)}  -> qs[row][col] = q | s<<16
// y=1: parts {k (128-255),      v (256-383)}  -> kv[row][col] = k | v<<16
__global__ __launch_bounds__(256) void qkvs_mfma_kernel(
    const unsigned short* __restrict__ hb, const unsigned short* __restrict__ wT,
    const float* __restrict__ bq, const float* __restrict__ bk,
    const float* __restrict__ bv, const float* __restrict__ bs,
    unsigned int* __restrict__ qs, unsigned int* __restrict__ kv)
{
    __shared__ char sA[64*256];   // [64][128] bf16, XOR-swizzled
    int row0 = blockIdx.x*64;
    for (int idx = threadIdx.x; idx < 1024; idx += 256){
        int row = idx >> 4, k16 = idx & 15;
        int byte = row*256 + k16*16;  byte ^= (row & 7) << 4;
        s16x8 val = {0,0,0,0,0,0,0,0};
        int grow = row0 + row;
        if (grow < N_NODES) val = *(const s16x8*)(hb + (size_t)grow*128 + k16*8);
        *(s16x8*)(sA + byte) = val;
    }
    __syncthreads();

    int w = threadIdx.x >> 6, l = threadIdx.x & 63;
    int y = blockIdx.y;
    int pb0 = y ? 128 : 0;
    int pb1 = y ? 256 : 384;

    f32x4 acc[4][4];
    #pragma unroll
    for (int rf=0;rf<4;++rf)
        #pragma unroll
        for (int cf=0;cf<4;++cf) acc[rf][cf] = (f32x4){0.f,0.f,0.f,0.f};

    s16x8 af[2][4], bf[2][4];
    #pragma unroll
    for (int rf=0;rf<4;++rf){
        int row = rf*16 + (l & 15);
        int byte = row*256 + (l >> 4)*16;  byte ^= (row & 7) << 4;
        af[0][rf] = *(const s16x8*)(sA + byte);
    }
    #pragma unroll
    for (int cf=0;cf<4;++cf){
        int nrow = ((cf < 2) ? pb0 : pb1) + (w<<5) + ((cf&1)<<4) + (l & 15);
        bf[0][cf] = *(const s16x8*)(wT + (size_t)nrow*128 + (l >> 4)*8);
    }
    #pragma unroll
    for (int kb = 0; kb < 4; ++kb){
        int cur = kb & 1, nxt = cur ^ 1;
        if (kb < 3){
            #pragma unroll
            for (int rf=0;rf<4;++rf){
                int row = rf*16 + (l & 15);
                int byte = row*256 + (kb+1)*64 + (l >> 4)*16;  byte ^= (row & 7) << 4;
                af[nxt][rf] = *(const s16x8*)(sA + byte);
            }
            #pragma unroll
            for (int cf=0;cf<4;++cf){
                int nrow = ((cf < 2) ? pb0 : pb1) + (w<<5) + ((cf&1)<<4) + (l & 15);
                bf[nxt][cf] = *(const s16x8*)(wT + (size_t)nrow*128 + (kb+1)*32 + (l >> 4)*8);
            }
        }
        #pragma unroll
        for (int rf=0;rf<4;++rf)
            #pragma unroll
            for (int cf=0;cf<4;++cf)
                acc[rf][cf] = __builtin_amdgcn_mfma_f32_16x16x32_bf16(af[cur][rf], bf[cur][cf], acc[rf][cf], 0, 0, 0);
    }

    const float* biasLo = y ? bk : bq;
    const float* biasHi = y ? bv : bs;
    unsigned int* outp  = y ? kv : qs;
    #pragma unroll
    for (int cp = 0; cp < 2; ++cp){
        int col = (w<<5) + (cp<<4) + (l & 15);
        float blo = biasLo[col], bhi = biasHi[col];
        #pragma unroll
        for (int rf=0;rf<4;++rf){
            #pragma unroll
            for (int r=0;r<4;++r){
                int row = row0 + rf*16 + ((l >> 4) << 2) + r;
                if (row < N_NODES){
                    float lo = acc[rf][cp][r]   + blo;
                    float hi = acc[rf][cp+2][r] + bhi;
                    outp[(size_t)row*128 + col] =
                        (unsigned int)f2bf(lo) | ((unsigned int)f2bf(hi) << 16);
                }
            }
        }
    }
}

// ---------------- attention + skip + LN1 fused: one wave per destination node -----------
// alpha = (q*scale).k[src] + qe.ea ; agg = (sum p*v + (sum p*ea)@Weff)/den ; pea[7]==den
__global__ __launch_bounds__(256) void attn_kernel(
    const unsigned int* __restrict__ qs, const unsigned int* __restrict__ kv,
    const float* __restrict__ weff_l, const int* __restrict__ rowptr,
    const int* __restrict__ srcs, const unsigned int* __restrict__ eab,
    const float* __restrict__ h,
    const float* __restrict__ n1g, const float* __restrict__ n1b,
    unsigned short* __restrict__ x1b)
{
    __shared__ float wf[8][DIM];
    for (int i = threadIdx.x; i < 8*DIM; i += 256) ((float*)wf)[i] = weff_l[i];
    __syncthreads();
    int wv = threadIdx.x >> 6, lane = threadIdx.x & 63;
    int n = blockIdx.x*4 + wv;
    if (n >= N_NODES) return;
    int d0 = lane*2;

    uint2 qsb = *(const uint2*)(qs + (size_t)n*DIM + d0);
    float q0 = bflo(qsb.x)*ATT_SCALE, q1 = bflo(qsb.y)*ATT_SCALE;
    float s0 = bfhi(qsb.x), s1 = bfhi(qsb.y);

    // qe[c] = sum_{d in head} (q*scale)_d * Weff[c][d]
    float qe[8];
    #pragma unroll
    for (int c = 0; c < 8; ++c){
        float2 wc = *(const float2*)&wf[c][d0];
        float p = q0*wc.x + q1*wc.y;
        p += __shfl_xor(p, 1); p += __shfl_xor(p, 2);
        p += __shfl_xor(p, 4); p += __shfl_xor(p, 8);
        qe[c] = p;
    }

    int beg = rowptr[n], end = rowptr[n+1], deg = end - beg;
    float m = -1e30f, den = 0.f, a0 = 0.f, a1 = 0.f;
    float pea0=0.f, pea1=0.f, pea2=0.f, pea3=0.f, pea4=0.f, pea5=0.f, pea6=0.f;

    for (int cb = 0; cb < deg; cb += 64){
        int cdeg = deg - cb; if (cdeg > 64) cdeg = 64;
        int base = beg + cb;
        int srcv = 0;
        if (cb + lane < deg) srcv = srcs[base + lane];
        uint2 kb0={0,0}, kb1={0,0}, kb2={0,0}, kb3={0,0};
        uint4 eb0={0,0,0,0}, eb1={0,0,0,0}, eb2={0,0,0,0}, eb3={0,0,0,0};

#define LOADS(c, jj) { int j_ = (jj); if (j_ < cdeg){ \
        int sv_ = __shfl(srcv, j_); \
        kb##c = *(const uint2*)(kv + (size_t)sv_*DIM + d0); \
        eb##c = *(const uint4*)(eab + (size_t)(base + j_)*4); } }

#define PROC(c, jj) { int j_ = (jj); if (j_ < cdeg){ \
        float k0_ = bflo(kb##c.x), k1_ = bflo(kb##c.y); \
        float p_ = q0*k0_ + q1*k1_; \
        p_ += __shfl_xor(p_, 1); p_ += __shfl_xor(p_, 2); \
        p_ += __shfl_xor(p_, 4); p_ += __shfl_xor(p_, 8); \
        float e0_=bflo(eb##c.x), e1_=bfhi(eb##c.x), e2_=bflo(eb##c.y), e3_=bfhi(eb##c.y); \
        float e4_=bflo(eb##c.z), e5_=bfhi(eb##c.z), e6_=bflo(eb##c.w); \
        float al_ = p_ + qe[7] + qe[0]*e0_ + qe[1]*e1_ + qe[2]*e2_ + qe[3]*e3_ \
                              + qe[4]*e4_ + qe[5]*e5_ + qe[6]*e6_; \
        if (!__all(al_ <= m + 8.f)){ \
            float nm_ = fmaxf(m, al_); float f_ = __expf(m - nm_); \
            den*=f_; a0*=f_; a1*=f_; \
            pea0*=f_; pea1*=f_; pea2*=f_; pea3*=f_; pea4*=f_; pea5*=f_; pea6*=f_; \
            m = nm_; } \
        float pp_ = __expf(al_ - m); \
        den += pp_; a0 += pp_*bfhi(kb##c.x); a1 += pp_*bfhi(kb##c.y); \
        pea0 += pp_*e0_; pea1 += pp_*e1_; pea2 += pp_*e2_; pea3 += pp_*e3_; \
        pea4 += pp_*e4_; pea5 += pp_*e5_; pea6 += pp_*e6_; } }

        LOADS(0, 0) LOADS(1, 1) LOADS(2, 2) LOADS(3, 3)
        for (int jb = 0; jb < cdeg; jb += 4){
            PROC(0, jb)     LOADS(0, jb+4)
            PROC(1, jb+1)   LOADS(1, jb+5)
            PROC(2, jb+2)   LOADS(2, jb+6)
            PROC(3, jb+3)   LOADS(3, jb+7)
        }
#undef LOADS
#undef PROC
    }

    float inv = (den > 0.f) ? 1.f/den : 0.f;
    float2 w0 = *(const float2*)&wf[0][d0];
    float2 w1c = *(const float2*)&wf[1][d0];
    float2 w2c = *(const float2*)&wf[2][d0];
    float2 w3c = *(const float2*)&wf[3][d0];
    float2 w4c = *(const float2*)&wf[4][d0];
    float2 w5c = *(const float2*)&wf[5][d0];
    float2 w6c = *(const float2*)&wf[6][d0];
    float2 w7c = *(const float2*)&wf[7][d0];
    float ev0 = pea0*w0.x + pea1*w1c.x + pea2*w2c.x + pea3*w3c.x
              + pea4*w4c.x + pea5*w5c.x + pea6*w6c.x + den*w7c.x;
    float ev1 = pea0*w0.y + pea1*w1c.y + pea2*w2c.y + pea3*w3c.y
              + pea4*w4c.y + pea5*w5c.y + pea6*w6c.y + den*w7c.y;

    float2 hv = *(const float2*)(h + (size_t)n*DIM + d0);
    float t0 = hv.x + (a0 + ev0)*inv + s0;
    float t1 = hv.y + (a1 + ev1)*inv + s1;
    // LN1
    float sum = t0 + t1, ss = t0*t0 + t1*t1;
    #pragma unroll
    for (int off = 1; off < 64; off <<= 1){
        sum += __shfl_xor(sum, off);
        ss  += __shfl_xor(ss,  off);
    }
    float mu = sum * (1.f/DIM);
    float rstd = rsqrtf(ss*(1.f/DIM) - mu*mu + LN_EPS);
    float o0 = (t0-mu)*rstd*n1g[d0]   + n1b[d0];
    float o1 = (t1-mu)*rstd*n1g[d0+1] + n1b[d0+1];
    unsigned int pk = (unsigned int)f2bf(o0) | ((unsigned int)f2bf(o1) << 16);
    *(unsigned int*)(x1b + (size_t)n*DIM + d0) = pk;
}

// ---------------- FFN via MFMA + LN2 + LN3 + act + residual ----------------
__global__ __launch_bounds__(256) void ffn_mfma_kernel(
    const unsigned short* __restrict__ x1b,
    const float* __restrict__ hin,
    const unsigned short* __restrict__ w1T, const float* __restrict__ b1,
    const unsigned short* __restrict__ w2T, const float* __restrict__ b2,
    const float* __restrict__ n2g, const float* __restrict__ n2b,
    const float* __restrict__ lng, const float* __restrict__ lnb,
    int apply_act, float* __restrict__ h, unsigned short* __restrict__ hb)
{
    __shared__ char smem[49152];
    char* sA   = smem;            // [64][128] bf16 swz (x1 tile)
    char* sMid = smem + 16384;    // [64][256] bf16 swz (mid) -> later ffout [64][128] f32 swz
    int row0 = blockIdx.x*64;
    for (int idx = threadIdx.x; idx < 1024; idx += 256){
        int row = idx >> 4, k16 = idx & 15;
        int byte = row*256 + k16*16;  byte ^= (row & 7) << 4;
        s16x8 val = {0,0,0,0,0,0,0,0};
        int grow = row0 + row;
        if (grow < N_NODES) val = *(const s16x8*)(x1b + (size_t)grow*128 + k16*8);
        *(s16x8*)(sA + byte) = val;
    }
    __syncthreads();

    int w = threadIdx.x >> 6, l = threadIdx.x & 63;

    // ---- GEMM1: mid = leaky(x1 @ W1 + b1); wave w -> cols w*64..+63
    {
        int n0 = w*64;
        f32x4 acc[4][4];
        #pragma unroll
        for (int rf=0;rf<4;++rf)
            #pragma unroll
            for (int cf=0;cf<4;++cf) acc[rf][cf] = (f32x4){0.f,0.f,0.f,0.f};
        s16x8 af[2][4], bfr[2][4];
        #pragma unroll
        for (int rf=0;rf<4;++rf){
            int row = rf*16 + (l & 15);
            int byte = row*256 + (l >> 4)*16;  byte ^= (row & 7) << 4;
            af[0][rf] = *(const s16x8*)(sA + byte);
        }
        #pragma unroll
        for (int cf=0;cf<4;++cf){
            int n = n0 + cf*16 + (l & 15);
            bfr[0][cf] = *(const s16x8*)(w1T + (size_t)n*128 + (l >> 4)*8);
        }
        #pragma unroll
        for (int kb = 0; kb < 4; ++kb){
            int cur = kb & 1, nxt = cur ^ 1;
            if (kb < 3){
                #pragma unroll
                for (int rf=0;rf<4;++rf){
                    int row = rf*16 + (l & 15);
                    int byte = row*256 + (kb+1)*64 + (l >> 4)*16;  byte ^= (row & 7) << 4;
                    af[nxt][rf] = *(const s16x8*)(sA + byte);
                }
                #pragma unroll
                for (int cf=0;cf<4;++cf){
                    int n = n0 + cf*16 + (l & 15);
                    bfr[nxt][cf] = *(const s16x8*)(w1T + (size_t)n*128 + (kb+1)*32 + (l >> 4)*8);
                }
            }
            #pragma unroll
            for (int rf=0;rf<4;++rf)
                #pragma unroll
                for (int cf=0;cf<4;++cf)
                    acc[rf][cf] = __builtin_amdgcn_mfma_f32_16x16x32_bf16(af[cur][rf], bfr[cur][cf], acc[rf][cf], 0, 0, 0);
        }
        #pragma unroll
        for (int cf=0;cf<4;++cf){
            int col = n0 + cf*16 + (l & 15);
            float bb = b1[col];
            #pragma unroll
            for (int rf=0;rf<4;++rf){
                #pragma unroll
                for (int r=0;r<4;++r){
                    int row = rf*16 + ((l >> 4) << 2) + r;
                    float val = leaky(acc[rf][cf][r] + bb);
                    int byte = row*512 + col*2;  byte ^= (row & 7) << 4;
                    *(unsigned short*)(sMid + byte) = f2bf(val);
                }
            }
        }
    }
    __syncthreads();

    // ---- GEMM2: ff = mid @ W2; wave w -> cols w*32..+31; K=256
    f32x4 acc2[2][4];
    {
        int n0 = w*32;
        #pragma unroll
        for (int cf=0;cf<2;++cf)
            #pragma unroll
            for (int rf=0;rf<4;++rf) acc2[cf][rf] = (f32x4){0.f,0.f,0.f,0.f};
        s16x8 af[2][4], bfr[2][2];
        #pragma unroll
        for (int rf=0;rf<4;++rf){
            int row = rf*16 + (l & 15);
            int byte = row*512 + (l >> 4)*16;  byte ^= (row & 7) << 4;
            af[0][rf] = *(const s16x8*)(sMid + byte);
        }
        #pragma unroll
        for (int cf=0;cf<2;++cf){
            int n = n0 + cf*16 + (l & 15);
            bfr[0][cf] = *(const s16x8*)(w2T + (size_t)n*256 + (l >> 4)*8);
        }
        #pragma unroll
        for (int kb = 0; kb < 8; ++kb){
            int cur = kb & 1, nxt = cur ^ 1;
            if (kb < 7){
                #pragma unroll
                for (int rf=0;rf<4;++rf){
                    int row = rf*16 + (l & 15);
                    int byte = row*512 + (kb+1)*64 + (l >> 4)*16;  byte ^= (row & 7) << 4;
                    af[nxt][rf] = *(const s16x8*)(sMid + byte);
                }
                #pragma unroll
                for (int cf=0;cf<2;++cf){
                    int n = n0 + cf*16 + (l & 15);
                    bfr[nxt][cf] = *(const s16x8*)(w2T + (size_t)n*256 + (kb+1)*32 + (l >> 4)*8);
                }
            }
            #pragma unroll
            for (int cf=0;cf<2;++cf)
                #pragma unroll
                for (int rf=0;rf<4;++rf)
                    acc2[cf][rf] = __builtin_amdgcn_mfma_f32_16x16x32_bf16(af[cur][rf], bfr[cur][cf], acc2[cf][rf], 0, 0, 0);
        }
    }
    __syncthreads();   // all GEMM2 reads of sMid done; reuse as ffout f32

    float* sFF = (float*)sMid;
    {
        int n0 = w*32;
        #pragma unroll
        for (int cf=0;cf<2;++cf){
            int col = n0 + cf*16 + (l & 15);
            float bb = b2[col];
            #pragma unroll
            for (int rf=0;rf<4;++rf){
                #pragma unroll
                for (int r=0;r<4;++r){
                    int row = rf*16 + ((l >> 4) << 2) + r;
                    int byte = row*512 + col*4;  byte ^= (row & 7) << 4;
                    *(float*)((char*)sFF + byte) = acc2[cf][rf][r] + bb;
                }
            }
        }
    }
    __syncthreads();

    // ---- LN chain: c = LN2(x1+ff), hn = LN3(c), act, h = hn + h_in
    int d0 = l*2;
    float g2a = n2g[d0], g2b = n2g[d0+1], be2a = n2b[d0], be2b = n2b[d0+1];
    float gla = lng[d0], glb = lng[d0+1], bla = lnb[d0], blb = lnb[d0+1];
    for (int i = 0; i < 16; ++i){
        int rr = w*16 + i;
        int grow = row0 + rr;
        if (grow >= N_NODES) break;
        int byte = rr*512 + d0*4;  byte ^= (rr & 7) << 4;
        float2 ff = *(float2*)((char*)sFF + byte);
        int byteA = rr*256 + d0*2;  byteA ^= (rr & 7) << 4;
        unsigned int xu = *(unsigned int*)(sA + byteA);   // x1 residual from LDS bf16
        float2 hr = *(const float2*)(hin + (size_t)grow*DIM + d0);
        float t0 = bflo(xu) + ff.x, t1 = bfhi(xu) + ff.y;
        float sum = t0 + t1, ss = t0*t0 + t1*t1;
        #pragma unroll
        for (int off = 1; off < 64; off <<= 1){
            sum += __shfl_xor(sum, off);
            ss  += __shfl_xor(ss,  off);
        }
        float mu = sum*(1.f/DIM);
        float rstd = rsqrtf(ss*(1.f/DIM) - mu*mu + LN_EPS);
        float c0 = (t0-mu)*rstd*g2a + be2a;
        float c1 = (t1-mu)*rstd*g2b + be2b;
        float sum2 = c0 + c1, ss2 = c0*c0 + c1*c1;
        #pragma unroll
        for (int off = 1; off < 64; off <<= 1){
            sum2 += __shfl_xor(sum2, off);
            ss2  += __shfl_xor(ss2,  off);
        }
        float mu2 = sum2*(1.f/DIM);
        float rstd2 = rsqrtf(ss2*(1.f/DIM) - mu2*mu2 + LN_EPS);
        float z0 = (c0-mu2)*rstd2*gla + bla;
        float z1 = (c1-mu2)*rstd2*glb + blb;
        if (apply_act){ z0 = leaky(z0); z1 = leaky(z1); }
        float o0 = z0 + hr.x, o1 = z1 + hr.y;
        *(float2*)(h + (size_t)grow*DIM + d0) = make_float2(o0, o1);
        unsigned int pk = (unsigned int)f2bf(o0) | ((unsigned int)f2bf(o1) << 16);
        *(unsigned int*)(hb + (size_t)grow*DIM + d0) = pk;
    }
}

extern "C" void kernel_launch(void* const* d_in, const int* in_sizes, int n_in,
                              void* d_out, int out_size, void* d_ws, size_t ws_size,
                              hipStream_t stream)
{
    const int*   edge_index = (const int*)  d_in[1];
    const float* edge_attr  = (const float*)d_in[2];
    const float* node_table = (const float*)d_in[3];
    const float* Wee = (const float*)d_in[4];
    const float* bee = (const float*)d_in[5];
    const float* Wq  = (const float*)d_in[6];  const float* bq = (const float*)d_in[7];
    const float* Wk  = (const float*)d_in[8];  const float* bk = (const float*)d_in[9];
    const float* Wv  = (const float*)d_in[10]; const float* bv = (const float*)d_in[11];
    const float* We  = (const float*)d_in[12]; const float* be = (const float*)d_in[13];
    const float* Ws  = (const float*)d_in[14]; const float* bs = (const float*)d_in[15];
    const float* W1  = (const float*)d_in[16]; const float* b1 = (const float*)d_in[17];
    const float* W2  = (const float*)d_in[18]; const float* b2 = (const float*)d_in[19];
    const float* n1g = (const float*)d_in[20]; const float* n1b = (const float*)d_in[21];
    const float* n2g = (const float*)d_in[22]; const float* n2b = (const float*)d_in[23];
    const float* lng = (const float*)d_in[24]; const float* lnb = (const float*)d_in[25];

    float* h = (float*)d_out;

    char* ws = (char*)d_ws;
    size_t off = 0;
    auto alloc = [&](size_t bytes)->void*{
        void* p = ws + off;
        off += (bytes + 255) & ~(size_t)255;
        return p;
    };
    unsigned int*   qs   = (unsigned int*)  alloc(sizeof(int)*(size_t)N_NODES*DIM);
    unsigned int*   kv   = (unsigned int*)  alloc(sizeof(int)*(size_t)N_NODES*DIM);
    unsigned short* hb   = (unsigned short*)alloc(sizeof(short)*(size_t)N_NODES*DIM);
    unsigned short* x1b  = (unsigned short*)alloc(sizeof(short)*(size_t)N_NODES*DIM);
    unsigned int*   eab  = (unsigned int*)  alloc(sizeof(int)*(size_t)N_EDGES*4);
    unsigned short* wqkvsT = (unsigned short*)alloc(sizeof(short)*NLAYER*512*128);
    unsigned short* w1T    = (unsigned short*)alloc(sizeof(short)*NLAYER*256*128);
    unsigned short* w2T    = (unsigned short*)alloc(sizeof(short)*NLAYER*128*256);
    float* weff = (float*)alloc(sizeof(float)*NLAYER*8*DIM);
    int* rowptr = (int*)alloc(sizeof(int)*(N_NODES+1));
    int* cnt    = (int*)alloc(sizeof(int)*N_NODES);
    int* fill   = (int*)alloc(sizeof(int)*N_NODES);
    int* srcs   = (int*)alloc(sizeof(int)*N_EDGES);

    const int* srcIdx = edge_index;
    const int* dstIdx = edge_index + N_EDGES;

    init_h_kernel<<<(N_NODES*DIM+255)/256, 256, 0, stream>>>(node_table, h, hb);
    zero2_kernel<<<(N_NODES+255)/256, 256, 0, stream>>>(cnt, fill);
    count_kernel<<<(N_EDGES+255)/256, 256, 0, stream>>>(dstIdx, cnt);
    scan_kernel<<<1, 1024, 0, stream>>>(cnt, rowptr);
    scatter_kernel<<<(N_EDGES+255)/256, 256, 0, stream>>>(srcIdx, dstIdx, edge_attr,
                                                          rowptr, fill, srcs, eab);
    prepw_kernel<<<(NLAYER*131072+255)/256, 256, 0, stream>>>(Wq, Wk, Wv, Ws, W1, W2,
                                                              wqkvsT, w1T, w2T);
    weff_all_kernel<<<NLAYER, 128, 0, stream>>>(Wee, bee, We, be, weff);

    int tiles = (N_NODES + 63)/64;
    for (int l = 0; l < NLAYER; ++l){
        qkvs_mfma_kernel<<<dim3(tiles, 2), 256, 0, stream>>>(hb,
            wqkvsT + (size_t)l*65536,
            bq + (size_t)l*DIM, bk + (size_t)l*DIM, bv + (size_t)l*DIM, bs + (size_t)l*DIM,
            qs, kv);
        attn_kernel<<<(N_NODES+3)/4, 256, 0, stream>>>(qs, kv,
            weff + (size_t)l*8*DIM, rowptr, srcs, eab, h,
            n1g + (size_t)l*DIM, n1b + (size_t)l*DIM, x1b);
        ffn_mfma_kernel<<<tiles, 256, 0, stream>>>(x1b, h,
            w1T + (size_t)l*32768, b1 + (size_t)l*2*DIM,
            w2T + (size_t)l*32768, b2 + (size_t)l*DIM,
            n2g + (size_t)l*DIM, n2b + (size_t)l*DIM,
            lng + (size_t)l*DIM, lnb + (size_t)l*DIM,
            (l < NLAYER-1) ? 1 : 0, h, hb);
    }
}

// Round 6
// 877.075 us; speedup vs baseline: 1.0992x; 1.0246x over previous
//
#include <hip/hip_runtime.h>
#include <hip/hip_bf16.h>
#include <math.h>

#define N_NODES 50000
#define N_EDGES 500000
#define DIM     128
#define NLAYER  4
#define NEFEAT  7

static constexpr float LN_EPS    = 1e-5f;
static constexpr float ATT_SCALE = 0.17677669529663687f;  // 1/sqrt(32)

typedef short s16x8 __attribute__((ext_vector_type(8)));   // 8 bf16 (4 VGPR) MFMA A/B frag
typedef float f32x4 __attribute__((ext_vector_type(4)));   // MFMA C/D frag

static __device__ __forceinline__ float leaky(float x){ return x >= 0.f ? x : 0.01f*x; }

static __device__ __forceinline__ unsigned short f2bf(float f){
    __hip_bfloat16 b = __float2bfloat16(f);
    return *reinterpret_cast<unsigned short*>(&b);
}
static __device__ __forceinline__ float bflo(unsigned int u){ return __uint_as_float(u << 16); }
static __device__ __forceinline__ float bfhi(unsigned int u){ return __uint_as_float(u & 0xFFFF0000u); }

// ---------------- init h = node_table[0] broadcast (fp32 + bf16 shadow) ----------------
__global__ void init_h_kernel(const float* __restrict__ node_table,
                              float* __restrict__ h, unsigned short* __restrict__ hb){
    int i = blockIdx.x*blockDim.x + threadIdx.x;
    if (i < N_NODES*DIM){
        float v = node_table[i & (DIM-1)];
        h[i]  = v;
        hb[i] = f2bf(v);
    }
}

// ---------------- CSR build ----------------
__global__ void zero2_kernel(int* __restrict__ a, int* __restrict__ b){
    int i = blockIdx.x*blockDim.x + threadIdx.x;
    if (i < N_NODES){ a[i] = 0; b[i] = 0; }
}

__global__ void count_kernel(const int* __restrict__ dst, int* __restrict__ cnt){
    int e = blockIdx.x*blockDim.x + threadIdx.x;
    if (e < N_EDGES) atomicAdd(&cnt[dst[e]], 1);
}

__global__ void scan_kernel(const int* __restrict__ cnt, int* __restrict__ rowptr){
    __shared__ int wsum[16];
    __shared__ int runsh;
    if (threadIdx.x == 0) runsh = 0;
    __syncthreads();
    int lane = threadIdx.x & 63, wid = threadIdx.x >> 6;
    for (int base = 0; base < N_NODES; base += 1024){
        int i = base + (int)threadIdx.x;
        int vv = (i < N_NODES) ? cnt[i] : 0;
        int s = vv;
        #pragma unroll
        for (int off = 1; off < 64; off <<= 1){
            int t = __shfl_up(s, off);
            if (lane >= off) s += t;
        }
        if (lane == 63) wsum[wid] = s;
        __syncthreads();
        if (wid == 0 && lane < 16){
            int x = wsum[lane];
            #pragma unroll
            for (int off = 1; off < 16; off <<= 1){
                int t = __shfl_up(x, off);
                if (lane >= off) x += t;
            }
            wsum[lane] = x;
        }
        __syncthreads();
        int wpre = (wid == 0) ? 0 : wsum[wid-1];
        int run  = runsh;
        if (i < N_NODES) rowptr[i] = run + wpre + s - vv;   // exclusive
        __syncthreads();
        if (threadIdx.x == 0) runsh = run + wsum[15];
        __syncthreads();
    }
    if (threadIdx.x == 0) rowptr[N_NODES] = runsh;
}

__global__ void scatter_kernel(const int* __restrict__ src, const int* __restrict__ dst,
                               const float* __restrict__ edge_attr,
                               const int* __restrict__ rowptr, int* __restrict__ fill,
                               int* __restrict__ srcs, unsigned int* __restrict__ eab){
    int e = blockIdx.x*blockDim.x + threadIdx.x;
    if (e >= N_EDGES) return;
    int d   = dst[e];
    int pos = rowptr[d] + atomicAdd(&fill[d], 1);
    srcs[pos] = src[e];
    const float* a = edge_attr + (size_t)e*NEFEAT;
    uint4 u;
    u.x = (unsigned int)f2bf(a[0]) | ((unsigned int)f2bf(a[1]) << 16);
    u.y = (unsigned int)f2bf(a[2]) | ((unsigned int)f2bf(a[3]) << 16);
    u.z = (unsigned int)f2bf(a[4]) | ((unsigned int)f2bf(a[5]) << 16);
    u.w = (unsigned int)f2bf(a[6]) | (0x3F80u << 16);   // bias slot = 1.0
    *(uint4*)(eab + (size_t)pos*4) = u;
}

// ---------------- Weff[l] = [Wee@We_l ; bee@We_l + be_l]  (8 x 128), all layers ----------
__global__ void weff_all_kernel(const float* __restrict__ Wee, const float* __restrict__ bee,
                                const float* __restrict__ We, const float* __restrict__ be,
                                float* __restrict__ weff){
    int l = blockIdx.x;
    int d = threadIdx.x;  // 128 threads
    const float* We_l = We + (size_t)l*DIM*DIM;
    float* out = weff + (size_t)l*8*DIM;
    for (int c = 0; c < NEFEAT; ++c){
        float s = 0.f;
        for (int t = 0; t < DIM; ++t) s += Wee[c*DIM + t] * We_l[t*DIM + d];
        out[c*DIM + d] = s;
    }
    float s = 0.f;
    for (int t = 0; t < DIM; ++t) s += bee[t] * We_l[t*DIM + d];
    out[7*DIM + d] = s + be[l*DIM + d];
}

// ---------------- weight prep: bf16 transposed copies ----------------
__global__ void prepw_kernel(const float* __restrict__ Wq, const float* __restrict__ Wk,
                             const float* __restrict__ Wv, const float* __restrict__ Ws,
                             const float* __restrict__ W1, const float* __restrict__ W2,
                             unsigned short* __restrict__ wqkvsT,
                             unsigned short* __restrict__ w1T,
                             unsigned short* __restrict__ w2T){
    int tid = blockIdx.x*blockDim.x + threadIdx.x;
    if (tid >= NLAYER*131072) return;
    int l = tid >> 17;
    int r = tid & 131071;
    if (r < 65536){
        int n = r >> 7, k = r & 127;
        int p = n >> 7, nn = n & 127;
        const float* W = (p==0)?Wq:(p==1)?Wk:(p==2)?Wv:Ws;
        float val = W[(size_t)l*DIM*DIM + (size_t)k*DIM + nn];
        wqkvsT[(size_t)l*65536 + (size_t)n*128 + k] = f2bf(val);
    } else if (r < 98304){
        int r2 = r - 65536;
        int n = r2 >> 7, k = r2 & 127;
        float val = W1[(size_t)l*32768 + (size_t)k*256 + n];
        w1T[(size_t)l*32768 + (size_t)n*128 + k] = f2bf(val);
    } else {
        int r2 = r - 98304;
        int n = r2 >> 8, k = r2 & 255;
        float val = W2[(size_t)l*32768 + (size_t)k*128 + n];
        w2T[(size_t)l*32768 + (size_t)n*256 + k] = f2bf(val);
    }
}

// ---------------- QKVS GEMM via MFMA: [N,128]bf16 @ [128,512]bf16 ----------------
// grid (tiles, 2); 4 waves, 64 rows/tile.
// y=0: parts {q, s}  -> qs[row][col] = q | s<<16
// y=1: parts {k, v}  -> kv[row][col] = k | v<<16
__global__ __launch_bounds__(256) void qkvs_mfma_kernel(
    const unsigned short* __restrict__ hb, const unsigned short* __restrict__ wT,
    const float* __restrict__ bq, const float* __restrict__ bk,
    const float* __restrict__ bv, const float* __restrict__ bs,
    unsigned int* __restrict__ qs, unsigned int* __restrict__ kv)
{
    __shared__ char sA[64*256];   // [64][128] bf16, XOR-swizzled
    int row0 = blockIdx.x*64;
    for (int idx = threadIdx.x; idx < 1024; idx += 256){
        int row = idx >> 4, k16 = idx & 15;
        int byte = row*256 + k16*16;  byte ^= (row & 7) << 4;
        s16x8 val = {0,0,0,0,0,0,0,0};
        int grow = row0 + row;
        if (grow < N_NODES) val = *(const s16x8*)(hb + (size_t)grow*128 + k16*8);
        *(s16x8*)(sA + byte) = val;
    }
    __syncthreads();

    int w = threadIdx.x >> 6, l = threadIdx.x & 63;
    int y = blockIdx.y;
    int pb0 = y ? 128 : 0;
    int pb1 = y ? 256 : 384;

    f32x4 acc[4][4];
    #pragma unroll
    for (int rf=0;rf<4;++rf)
        #pragma unroll
        for (int cf=0;cf<4;++cf) acc[rf][cf] = (f32x4){0.f,0.f,0.f,0.f};

    s16x8 af[2][4], bf[2][4];
    #pragma unroll
    for (int rf=0;rf<4;++rf){
        int row = rf*16 + (l & 15);
        int byte = row*256 + (l >> 4)*16;  byte ^= (row & 7) << 4;
        af[0][rf] = *(const s16x8*)(sA + byte);
    }
    #pragma unroll
    for (int cf=0;cf<4;++cf){
        int nrow = ((cf < 2) ? pb0 : pb1) + (w<<5) + ((cf&1)<<4) + (l & 15);
        bf[0][cf] = *(const s16x8*)(wT + (size_t)nrow*128 + (l >> 4)*8);
    }
    #pragma unroll
    for (int kb = 0; kb < 4; ++kb){
        int cur = kb & 1, nxt = cur ^ 1;
        if (kb < 3){
            #pragma unroll
            for (int rf=0;rf<4;++rf){
                int row = rf*16 + (l & 15);
                int byte = row*256 + (kb+1)*64 + (l >> 4)*16;  byte ^= (row & 7) << 4;
                af[nxt][rf] = *(const s16x8*)(sA + byte);
            }
            #pragma unroll
            for (int cf=0;cf<4;++cf){
                int nrow = ((cf < 2) ? pb0 : pb1) + (w<<5) + ((cf&1)<<4) + (l & 15);
                bf[nxt][cf] = *(const s16x8*)(wT + (size_t)nrow*128 + (kb+1)*32 + (l >> 4)*8);
            }
        }
        #pragma unroll
        for (int rf=0;rf<4;++rf)
            #pragma unroll
            for (int cf=0;cf<4;++cf)
                acc[rf][cf] = __builtin_amdgcn_mfma_f32_16x16x32_bf16(af[cur][rf], bf[cur][cf], acc[rf][cf], 0, 0, 0);
    }

    const float* biasLo = y ? bk : bq;
    const float* biasHi = y ? bv : bs;
    unsigned int* outp  = y ? kv : qs;
    #pragma unroll
    for (int cp = 0; cp < 2; ++cp){
        int col = (w<<5) + (cp<<4) + (l & 15);
        float blo = biasLo[col], bhi = biasHi[col];
        #pragma unroll
        for (int rf=0;rf<4;++rf){
            #pragma unroll
            for (int r=0;r<4;++r){
                int row = row0 + rf*16 + ((l >> 4) << 2) + r;
                if (row < N_NODES){
                    float lo = acc[rf][cp][r]   + blo;
                    float hi = acc[rf][cp+2][r] + bhi;
                    outp[(size_t)row*128 + col] =
                        (unsigned int)f2bf(lo) | ((unsigned int)f2bf(hi) << 16);
                }
            }
        }
    }
}

// ---------------- attention + skip + LN1 fused: one wave per destination node -----------
// alpha = (q*scale).k[src] + qe.ea ; agg = (sum p*v + (sum p*ea)@Weff)/den ; pea[7]==den
// Simple branchless online softmax; TLP (not manual ILP) hides gather latency.
__global__ __launch_bounds__(512) void attn_kernel(
    const unsigned int* __restrict__ qs, const unsigned int* __restrict__ kv,
    const float* __restrict__ weff_l, const int* __restrict__ rowptr,
    const int* __restrict__ srcs, const unsigned int* __restrict__ eab,
    const float* __restrict__ h,
    const float* __restrict__ n1g, const float* __restrict__ n1b,
    unsigned short* __restrict__ x1b)
{
    __shared__ float wf[8][DIM];
    for (int i = threadIdx.x; i < 8*DIM; i += 512) ((float*)wf)[i] = weff_l[i];
    __syncthreads();
    int wv = threadIdx.x >> 6, lane = threadIdx.x & 63;
    int n = blockIdx.x*8 + wv;
    if (n >= N_NODES) return;
    int d0 = lane*2;

    uint2 qsb = *(const uint2*)(qs + (size_t)n*DIM + d0);
    float q0 = bflo(qsb.x)*ATT_SCALE, q1 = bflo(qsb.y)*ATT_SCALE;
    float s0 = bfhi(qsb.x), s1 = bfhi(qsb.y);

    // qe[c] = sum_{d in head} (q*scale)_d * Weff[c][d]  (head = 16-lane group)
    float qe[8];
    #pragma unroll
    for (int c = 0; c < 8; ++c){
        float2 wc = *(const float2*)&wf[c][d0];
        float p = q0*wc.x + q1*wc.y;
        p += __shfl_xor(p, 1); p += __shfl_xor(p, 2);
        p += __shfl_xor(p, 4); p += __shfl_xor(p, 8);
        qe[c] = p;
    }

    int beg = rowptr[n], end = rowptr[n+1], deg = end - beg;
    float m = -1e30f, den = 0.f, a0 = 0.f, a1 = 0.f;
    float pea0=0.f, pea1=0.f, pea2=0.f, pea3=0.f, pea4=0.f, pea5=0.f, pea6=0.f;

    for (int cb = 0; cb < deg; cb += 64){
        int base = beg + cb;
        int cdeg = deg - cb; if (cdeg > 64) cdeg = 64;
        int srcv = 0;
        if (cb + lane < deg) srcv = srcs[base + lane];
        for (int j = 0; j < cdeg; ++j){
            int sv = __shfl(srcv, j);
            uint2 kva = *(const uint2*)(kv + (size_t)sv*DIM + d0);
            uint4 eu  = *(const uint4*)(eab + ((size_t)(base + j) << 2));
            float e0=bflo(eu.x), e1=bfhi(eu.x), e2=bflo(eu.y), e3=bfhi(eu.y);
            float e4=bflo(eu.z), e5=bfhi(eu.z), e6=bflo(eu.w);
            float p = q0*bflo(kva.x) + q1*bflo(kva.y);
            p += __shfl_xor(p, 1); p += __shfl_xor(p, 2);
            p += __shfl_xor(p, 4); p += __shfl_xor(p, 8);   // per-head (16-lane) dot
            float al = p + qe[7] + qe[0]*e0 + qe[1]*e1 + qe[2]*e2 + qe[3]*e3
                                + qe[4]*e4 + qe[5]*e5 + qe[6]*e6;
            float nm = fmaxf(m, al);
            float f  = __expf(m - nm);
            float pp = __expf(al - nm);
            den  = den*f  + pp;
            a0   = a0*f   + pp*bfhi(kva.x);
            a1   = a1*f   + pp*bfhi(kva.y);
            pea0 = pea0*f + pp*e0;
            pea1 = pea1*f + pp*e1;
            pea2 = pea2*f + pp*e2;
            pea3 = pea3*f + pp*e3;
            pea4 = pea4*f + pp*e4;
            pea5 = pea5*f + pp*e5;
            pea6 = pea6*f + pp*e6;
            m = nm;
        }
    }

    float inv = (den > 0.f) ? 1.f/den : 0.f;   // empty segment -> zeros
    float ev0, ev1;
    {
        float2 w0 = *(const float2*)&wf[0][d0];
        float2 w1c = *(const float2*)&wf[1][d0];
        float2 w2c = *(const float2*)&wf[2][d0];
        float2 w3c = *(const float2*)&wf[3][d0];
        float2 w4c = *(const float2*)&wf[4][d0];
        float2 w5c = *(const float2*)&wf[5][d0];
        float2 w6c = *(const float2*)&wf[6][d0];
        float2 w7c = *(const float2*)&wf[7][d0];
        ev0 = pea0*w0.x + pea1*w1c.x + pea2*w2c.x + pea3*w3c.x
            + pea4*w4c.x + pea5*w5c.x + pea6*w6c.x + den*w7c.x;
        ev1 = pea0*w0.y + pea1*w1c.y + pea2*w2c.y + pea3*w3c.y
            + pea4*w4c.y + pea5*w5c.y + pea6*w6c.y + den*w7c.y;
    }

    float2 hv = *(const float2*)(h + (size_t)n*DIM + d0);
    float t0 = hv.x + (a0 + ev0)*inv + s0;
    float t1 = hv.y + (a1 + ev1)*inv + s1;
    // LN1
    float sum = t0 + t1, ss = t0*t0 + t1*t1;
    #pragma unroll
    for (int off = 1; off < 64; off <<= 1){
        sum += __shfl_xor(sum, off);
        ss  += __shfl_xor(ss,  off);
    }
    float mu = sum * (1.f/DIM);
    float rstd = rsqrtf(ss*(1.f/DIM) - mu*mu + LN_EPS);
    float o0 = (t0-mu)*rstd*n1g[d0]   + n1b[d0];
    float o1 = (t1-mu)*rstd*n1g[d0+1] + n1b[d0+1];
    unsigned int pk = (unsigned int)f2bf(o0) | ((unsigned int)f2bf(o1) << 16);
    *(unsigned int*)(x1b + (size_t)n*DIM + d0) = pk;
}

// ---------------- FFN via MFMA + LN2 + LN3 + act + residual ----------------
__global__ __launch_bounds__(256) void ffn_mfma_kernel(
    const unsigned short* __restrict__ x1b,
    const float* __restrict__ hin,
    const unsigned short* __restrict__ w1T, const float* __restrict__ b1,
    const unsigned short* __restrict__ w2T, const float* __restrict__ b2,
    const float* __restrict__ n2g, const float* __restrict__ n2b,
    const float* __restrict__ lng, const float* __restrict__ lnb,
    int apply_act, float* __restrict__ h, unsigned short* __restrict__ hb)
{
    __shared__ char smem[49152];
    char* sA   = smem;            // [64][128] bf16 swz (x1 tile)
    char* sMid = smem + 16384;    // [64][256] bf16 swz (mid) -> later ffout [64][128] f32 swz
    int row0 = blockIdx.x*64;
    for (int idx = threadIdx.x; idx < 1024; idx += 256){
        int row = idx >> 4, k16 = idx & 15;
        int byte = row*256 + k16*16;  byte ^= (row & 7) << 4;
        s16x8 val = {0,0,0,0,0,0,0,0};
        int grow = row0 + row;
        if (grow < N_NODES) val = *(const s16x8*)(x1b + (size_t)grow*128 + k16*8);
        *(s16x8*)(sA + byte) = val;
    }
    __syncthreads();

    int w = threadIdx.x >> 6, l = threadIdx.x & 63;

    // ---- GEMM1: mid = leaky(x1 @ W1 + b1); wave w -> cols w*64..+63
    {
        int n0 = w*64;
        f32x4 acc[4][4];
        #pragma unroll
        for (int rf=0;rf<4;++rf)
            #pragma unroll
            for (int cf=0;cf<4;++cf) acc[rf][cf] = (f32x4){0.f,0.f,0.f,0.f};
        s16x8 af[2][4], bfr[2][4];
        #pragma unroll
        for (int rf=0;rf<4;++rf){
            int row = rf*16 + (l & 15);
            int byte = row*256 + (l >> 4)*16;  byte ^= (row & 7) << 4;
            af[0][rf] = *(const s16x8*)(sA + byte);
        }
        #pragma unroll
        for (int cf=0;cf<4;++cf){
            int n = n0 + cf*16 + (l & 15);
            bfr[0][cf] = *(const s16x8*)(w1T + (size_t)n*128 + (l >> 4)*8);
        }
        #pragma unroll
        for (int kb = 0; kb < 4; ++kb){
            int cur = kb & 1, nxt = cur ^ 1;
            if (kb < 3){
                #pragma unroll
                for (int rf=0;rf<4;++rf){
                    int row = rf*16 + (l & 15);
                    int byte = row*256 + (kb+1)*64 + (l >> 4)*16;  byte ^= (row & 7) << 4;
                    af[nxt][rf] = *(const s16x8*)(sA + byte);
                }
                #pragma unroll
                for (int cf=0;cf<4;++cf){
                    int n = n0 + cf*16 + (l & 15);
                    bfr[nxt][cf] = *(const s16x8*)(w1T + (size_t)n*128 + (kb+1)*32 + (l >> 4)*8);
                }
            }
            #pragma unroll
            for (int rf=0;rf<4;++rf)
                #pragma unroll
                for (int cf=0;cf<4;++cf)
                    acc[rf][cf] = __builtin_amdgcn_mfma_f32_16x16x32_bf16(af[cur][rf], bfr[cur][cf], acc[rf][cf], 0, 0, 0);
        }
        #pragma unroll
        for (int cf=0;cf<4;++cf){
            int col = n0 + cf*16 + (l & 15);
            float bb = b1[col];
            #pragma unroll
            for (int rf=0;rf<4;++rf){
                #pragma unroll
                for (int r=0;r<4;++r){
                    int row = rf*16 + ((l >> 4) << 2) + r;
                    float val = leaky(acc[rf][cf][r] + bb);
                    int byte = row*512 + col*2;  byte ^= (row & 7) << 4;
                    *(unsigned short*)(sMid + byte) = f2bf(val);
                }
            }
        }
    }
    __syncthreads();

    // ---- GEMM2: ff = mid @ W2; wave w -> cols w*32..+31; K=256
    f32x4 acc2[2][4];
    {
        int n0 = w*32;
        #pragma unroll
        for (int cf=0;cf<2;++cf)
            #pragma unroll
            for (int rf=0;rf<4;++rf) acc2[cf][rf] = (f32x4){0.f,0.f,0.f,0.f};
        s16x8 af[2][4], bfr[2][2];
        #pragma unroll
        for (int rf=0;rf<4;++rf){
            int row = rf*16 + (l & 15);
            int byte = row*512 + (l >> 4)*16;  byte ^= (row & 7) << 4;
            af[0][rf] = *(const s16x8*)(sMid + byte);
        }
        #pragma unroll
        for (int cf=0;cf<2;++cf){
            int n = n0 + cf*16 + (l & 15);
            bfr[0][cf] = *(const s16x8*)(w2T + (size_t)n*256 + (l >> 4)*8);
        }
        #pragma unroll
        for (int kb = 0; kb < 8; ++kb){
            int cur = kb & 1, nxt = cur ^ 1;
            if (kb < 7){
                #pragma unroll
                for (int rf=0;rf<4;++rf){
                    int row = rf*16 + (l & 15);
                    int byte = row*512 + (kb+1)*64 + (l >> 4)*16;  byte ^= (row & 7) << 4;
                    af[nxt][rf] = *(const s16x8*)(sMid + byte);
                }
                #pragma unroll
                for (int cf=0;cf<2;++cf){
                    int n = n0 + cf*16 + (l & 15);
                    bfr[nxt][cf] = *(const s16x8*)(w2T + (size_t)n*256 + (kb+1)*32 + (l >> 4)*8);
                }
            }
            #pragma unroll
            for (int cf=0;cf<2;++cf)
                #pragma unroll
                for (int rf=0;rf<4;++rf)
                    acc2[cf][rf] = __builtin_amdgcn_mfma_f32_16x16x32_bf16(af[cur][rf], bfr[cur][cf], acc2[cf][rf], 0, 0, 0);
        }
    }
    __syncthreads();   // all GEMM2 reads of sMid done; reuse as ffout f32

    float* sFF = (float*)sMid;
    {
        int n0 = w*32;
        #pragma unroll
        for (int cf=0;cf<2;++cf){
            int col = n0 + cf*16 + (l & 15);
            float bb = b2[col];
            #pragma unroll
            for (int rf=0;rf<4;++rf){
                #pragma unroll
                for (int r=0;r<4;++r){
                    int row = rf*16 + ((l >> 4) << 2) + r;
                    int byte = row*512 + col*4;  byte ^= (row & 7) << 4;
                    *(float*)((char*)sFF + byte) = acc2[cf][rf][r] + bb;
                }
            }
        }
    }
    __syncthreads();

    // ---- LN chain: c = LN2(x1+ff), hn = LN3(c), act, h = hn + h_in
    int d0 = l*2;
    float g2a = n2g[d0], g2b = n2g[d0+1], be2a = n2b[d0], be2b = n2b[d0+1];
    float gla = lng[d0], glb = lng[d0+1], bla = lnb[d0], blb = lnb[d0+1];
    for (int i = 0; i < 16; ++i){
        int rr = w*16 + i;
        int grow = row0 + rr;
        if (grow >= N_NODES) break;
        int byte = rr*512 + d0*4;  byte ^= (rr & 7) << 4;
        float2 ff = *(float2*)((char*)sFF + byte);
        int byteA = rr*256 + d0*2;  byteA ^= (rr & 7) << 4;
        unsigned int xu = *(unsigned int*)(sA + byteA);   // x1 residual from LDS bf16
        float2 hr = *(const float2*)(hin + (size_t)grow*DIM + d0);
        float t0 = bflo(xu) + ff.x, t1 = bfhi(xu) + ff.y;
        float sum = t0 + t1, ss = t0*t0 + t1*t1;
        #pragma unroll
        for (int off = 1; off < 64; off <<= 1){
            sum += __shfl_xor(sum, off);
            ss  += __shfl_xor(ss,  off);
        }
        float mu = sum*(1.f/DIM);
        float rstd = rsqrtf(ss*(1.f/DIM) - mu*mu + LN_EPS);
        float c0 = (t0-mu)*rstd*g2a + be2a;
        float c1 = (t1-mu)*rstd*g2b + be2b;
        float sum2 = c0 + c1, ss2 = c0*c0 + c1*c1;
        #pragma unroll
        for (int off = 1; off < 64; off <<= 1){
            sum2 += __shfl_xor(sum2, off);
            ss2  += __shfl_xor(ss2,  off);
        }
        float mu2 = sum2*(1.f/DIM);
        float rstd2 = rsqrtf(ss2*(1.f/DIM) - mu2*mu2 + LN_EPS);
        float z0 = (c0-mu2)*rstd2*gla + bla;
        float z1 = (c1-mu2)*rstd2*glb + blb;
        if (apply_act){ z0 = leaky(z0); z1 = leaky(z1); }
        float o0 = z0 + hr.x, o1 = z1 + hr.y;
        *(float2*)(h + (size_t)grow*DIM + d0) = make_float2(o0, o1);
        unsigned int pk = (unsigned int)f2bf(o0) | ((unsigned int)f2bf(o1) << 16);
        *(unsigned int*)(hb + (size_t)grow*DIM + d0) = pk;
    }
}

extern "C" void kernel_launch(void* const* d_in, const int* in_sizes, int n_in,
                              void* d_out, int out_size, void* d_ws, size_t ws_size,
                              hipStream_t stream)
{
    const int*   edge_index = (const int*)  d_in[1];
    const float* edge_attr  = (const float*)d_in[2];
    const float* node_table = (const float*)d_in[3];
    const float* Wee = (const float*)d_in[4];
    const float* bee = (const float*)d_in[5];
    const float* Wq  = (const float*)d_in[6];  const float* bq = (const float*)d_in[7];
    const float* Wk  = (const float*)d_in[8];  const float* bk = (const float*)d_in[9];
    const float* Wv  = (const float*)d_in[10]; const float* bv = (const float*)d_in[11];
    const float* We  = (const float*)d_in[12]; const float* be = (const float*)d_in[13];
    const float* Ws  = (const float*)d_in[14]; const float* bs = (const float*)d_in[15];
    const float* W1  = (const float*)d_in[16]; const float* b1 = (const float*)d_in[17];
    const float* W2  = (const float*)d_in[18]; const float* b2 = (const float*)d_in[19];
    const float* n1g = (const float*)d_in[20]; const float* n1b = (const float*)d_in[21];
    const float* n2g = (const float*)d_in[22]; const float* n2b = (const float*)d_in[23];
    const float* lng = (const float*)d_in[24]; const float* lnb = (const float*)d_in[25];

    float* h = (float*)d_out;

    char* ws = (char*)d_ws;
    size_t off = 0;
    auto alloc = [&](size_t bytes)->void*{
        void* p = ws + off;
        off += (bytes + 255) & ~(size_t)255;
        return p;
    };
    unsigned int*   qs   = (unsigned int*)  alloc(sizeof(int)*(size_t)N_NODES*DIM);
    unsigned int*   kv   = (unsigned int*)  alloc(sizeof(int)*(size_t)N_NODES*DIM);
    unsigned short* hb   = (unsigned short*)alloc(sizeof(short)*(size_t)N_NODES*DIM);
    unsigned short* x1b  = (unsigned short*)alloc(sizeof(short)*(size_t)N_NODES*DIM);
    unsigned int*   eab  = (unsigned int*)  alloc(sizeof(int)*(size_t)N_EDGES*4);
    unsigned short* wqkvsT = (unsigned short*)alloc(sizeof(short)*NLAYER*512*128);
    unsigned short* w1T    = (unsigned short*)alloc(sizeof(short)*NLAYER*256*128);
    unsigned short* w2T    = (unsigned short*)alloc(sizeof(short)*NLAYER*128*256);
    float* weff = (float*)alloc(sizeof(float)*NLAYER*8*DIM);
    int* rowptr = (int*)alloc(sizeof(int)*(N_NODES+1));
    int* cnt    = (int*)alloc(sizeof(int)*N_NODES);
    int* fill   = (int*)alloc(sizeof(int)*N_NODES);
    int* srcs   = (int*)alloc(sizeof(int)*N_EDGES);

    const int* srcIdx = edge_index;
    const int* dstIdx = edge_index + N_EDGES;

    init_h_kernel<<<(N_NODES*DIM+255)/256, 256, 0, stream>>>(node_table, h, hb);
    zero2_kernel<<<(N_NODES+255)/256, 256, 0, stream>>>(cnt, fill);
    count_kernel<<<(N_EDGES+255)/256, 256, 0, stream>>>(dstIdx, cnt);
    scan_kernel<<<1, 1024, 0, stream>>>(cnt, rowptr);
    scatter_kernel<<<(N_EDGES+255)/256, 256, 0, stream>>>(srcIdx, dstIdx, edge_attr,
                                                          rowptr, fill, srcs, eab);
    prepw_kernel<<<(NLAYER*131072+255)/256, 256, 0, stream>>>(Wq, Wk, Wv, Ws, W1, W2,
                                                              wqkvsT, w1T, w2T);
    weff_all_kernel<<<NLAYER, 128, 0, stream>>>(Wee, bee, We, be, weff);

    int tiles = (N_NODES + 63)/64;
    for (int l = 0; l < NLAYER; ++l){
        qkvs_mfma_kernel<<<dim3(tiles, 2), 256, 0, stream>>>(hb,
            wqkvsT + (size_t)l*65536,
            bq + (size_t)l*DIM, bk + (size_t)l*DIM, bv + (size_t)l*DIM, bs + (size_t)l*DIM,
            qs, kv);
        attn_kernel<<<(N_NODES+7)/8, 512, 0, stream>>>(qs, kv,
            weff + (size_t)l*8*DIM, rowptr, srcs, eab, h,
            n1g + (size_t)l*DIM, n1b + (size_t)l*DIM, x1b);
        ffn_mfma_kernel<<<tiles, 256, 0, stream>>>(x1b, h,
            w1T + (size_t)l*32768, b1 + (size_t)l*2*DIM,
            w2T + (size_t)l*32768, b2 + (size_t)l*DIM,
            n2g + (size_t)l*DIM, n2b + (size_t)l*DIM,
            lng + (size_t)l*DIM, lnb + (size_t)l*DIM,
            (l < NLAYER-1) ? 1 : 0, h, hb);
    }
}